// Round 7
// baseline (243.422 us; speedup 1.0000x reference)
//
#include <hip/hip_runtime.h>
#include <hip/hip_fp16.h>

// GridEncoder (instant-NGP triplane hash grid), static config:
//   D=3, L=3, C=2, base_res=128, per_level_scale=2, hashmap=2^19,
//   align_corners=False, linear interp, B=2^21.
// All levels hash-index; hmap=2^19 -> mod == & 0x7FFFF.
//
// R1: naive fp32 -> kernel 543 us (total 587; fixed harness ~43 us).
// R2: half2 table + 3 level passes -> 62 us/pass @ 270 G req/s (L2-res).
// R4-R7: fused single-pass variants -> 15 req/pt floor, 127-184 us.
// R8: level-clustered fused, 2048 blk x PPT=4, VGPR=108, no scratch ->
//     gather 127 us @ 248 G req/s, FETCH 110 MB (launch-staggered cohorts
//     persistently mix levels -> L2-miss latency throttles request rate).
// R9-R12: every attempt to enlarge per-thread work or pin occupancy
//     (PPT=8, g-loop, waves_per_eu, launch_bounds min-waves) flipped the
//     allocator to a 64-VGPR target with arrays in scratch (WRITE 0.5-0.7
//     GB, 440-590 us). ONLY R8's exact shape (top-level PPT=4 body, no
//     wrapper loop, no occupancy attributes) gives VGPR=108 + zero scratch.
// R13: two dispatches x 1024 blocks with RUNTIME off arg: structure right
//     (no scratch, WRITE clean) but the runtime arg alone re-triggered the
//     allocator cliff: VGPR=184 -> 2 blk/CU -> only 512/1024 co-resident,
//     mixing inside each dispatch: FETCH 104 MB/disp, 87.5 us x 2.
// R14: off as TEMPLATE parameter (compile-time constant folds into address
//     math; body byte-equivalent to the VGPR=108 baseline). Two stream-
//     serialized dispatches x 1024 blocks = 4/CU x 256 CU fully co-resident;
//     per-level __syncthreads phase-locks the 2 MB level table in L2.

#define NPOINTS  2097152
#define HMASK    0x7FFFFu
#define PLANE    524288            // entries per level table
#define NTAB     (3 * PLANE)       // packed half2 entries (6 MB)
#define GBLOCKS  1024
#define LTHREADS (GBLOCKS * 256)   // 262144 threads per dispatch
#define PPT      4                 // points per thread (proven codegen)
#define DPOINTS  (PPT * LTHREADS)  // 2^20 points per dispatch

typedef float    floatx2 __attribute__((ext_vector_type(2)));
typedef float    floatx4 __attribute__((ext_vector_type(4)));
typedef unsigned uintx2  __attribute__((ext_vector_type(2)));
typedef unsigned uintx4  __attribute__((ext_vector_type(4)));

__device__ __forceinline__ unsigned pack2(float a, float b) {
    const __half2 h2 = __halves2half2(__float2half_rn(a), __float2half_rn(b));
    return *reinterpret_cast<const unsigned*>(&h2);
}

// ---- prepass: tbl[level*2^19 + h] = half2(b[h], b[PLANE+h]) ----
__global__ __launch_bounds__(256) void tp_convert_kernel(
    const float* __restrict__ tp, uintx4* __restrict__ tbl)
{
    const unsigned t = blockIdx.x * 256u + threadIdx.x;   // < NTAB/4
    const unsigned level = t >> 17;                       // 2^17 quads/level
    const unsigned i4    = (t & 131071u) << 2;
    const float* __restrict__ b = tp + level * (2u * PLANE);
    const floatx4 c0 = __builtin_nontemporal_load(
        reinterpret_cast<const floatx4*>(b + i4));
    const floatx4 c1 = __builtin_nontemporal_load(
        reinterpret_cast<const floatx4*>(b + PLANE + i4));
    uintx4 o;
    o.x = pack2(c0.x, c1.x);
    o.y = pack2(c0.y, c1.y);
    o.z = pack2(c0.z, c1.z);
    o.w = pack2(c0.w, c1.w);
    tbl[t] = o;
}

__device__ __forceinline__ unsigned sel4(uintx4 q, unsigned o) {
    const unsigned a = (o & 1u) ? q.y : q.x;
    const unsigned b = (o & 1u) ? q.w : q.z;
    return (o & 2u) ? b : a;
}

// ---- level-clustered fused gather (baseline codegen + constant offset) ----
template <int OFF>
__global__ __launch_bounds__(256) void grid_gather_kernel(
    const unsigned* __restrict__ tbl,
    const float* __restrict__ inputs,
    floatx2* __restrict__ out)
{
    const int t = OFF + blockIdx.x * 256 + threadIdx.x;

    float x0[PPT], y0[PPT], z0[PPT];
#pragma unroll
    for (int p = 0; p < PPT; ++p) {
        const int i = t + p * LTHREADS;
        const float x = __builtin_nontemporal_load(&inputs[3 * i + 0]);
        const float y = __builtin_nontemporal_load(&inputs[3 * i + 1]);
        const float z = __builtin_nontemporal_load(&inputs[3 * i + 2]);
        x0[p] = (x + 1.0f) * 0.5f;
        y0[p] = (y + 1.0f) * 0.5f;
        z0[p] = (z + 1.0f) * 0.5f;
    }

    float o0[PPT], o1[PPT];
#pragma unroll
    for (int p = 0; p < PPT; ++p) { o0[p] = 0.0f; o1[p] = 0.0f; }

#pragma unroll
    for (int level = 0; level < 3; ++level) {
        const float scale = (float)((128 << level) - 1);  // 127, 255, 511
        const unsigned lvl = (unsigned)level << 19;

#pragma unroll
        for (int p = 0; p < PPT; ++p) {
            const float px = fmaf(x0[p], scale, 0.5f);
            const float py = fmaf(y0[p], scale, 0.5f);
            const float pz = fmaf(z0[p], scale, 0.5f);
            const float fx = floorf(px), fy = floorf(py), fz = floorf(pz);
            const float rx = px - fx, ry = py - fy, rz = pz - fz;
            const unsigned gx = (unsigned)fx, gy = (unsigned)fy, gz = (unsigned)fz;

            const unsigned d = gx ^ (gx + 1u);            // 1,3,7,15,...
            const unsigned hy0 = gy * 2654435761u;
            const unsigned hy1 = (gy + 1u) * 2654435761u;
            const unsigned hz0 = gz * 805459861u;
            const unsigned hz1 = (gz + 1u) * 805459861u;

            unsigned P[4];
            P[0] = lvl | ((gx ^ hy0 ^ hz0) & HMASK);
            P[1] = lvl | ((gx ^ hy1 ^ hz0) & HMASK);
            P[2] = lvl | ((gx ^ hy0 ^ hz1) & HMASK);
            P[3] = lvl | ((gx ^ hy1 ^ hz1) & HMASK);

            // aligned 16B quad containing e0 (and e1 when d<=3)
            uintx4 q[4];
#pragma unroll
            for (int j = 0; j < 4; ++j)
                q[j] = *reinterpret_cast<const uintx4*>(tbl + (P[j] & ~3u));

            const float wx1 = rx, wx0 = 1.0f - rx;
            const float wy1 = ry, wy0 = 1.0f - ry;
            const float wz1 = rz, wz0 = 1.0f - rz;
            const float wyz[4] = { wy0 * wz0, wy1 * wz0, wy0 * wz1, wy1 * wz1 };

            unsigned e1v[4];
            if (d > 3u) {
                // distant partner: 4B loads
#pragma unroll
                for (int j = 0; j < 4; ++j) e1v[j] = tbl[P[j] ^ d];
            } else {
                // partner inside the quad
#pragma unroll
                for (int j = 0; j < 4; ++j) e1v[j] = sel4(q[j], (P[j] & 3u) ^ d);
            }

#pragma unroll
            for (int j = 0; j < 4; ++j) {
                const unsigned e0 = sel4(q[j], P[j] & 3u);
                const __half2 a = *reinterpret_cast<const __half2*>(&e0);
                const __half2 b = *reinterpret_cast<const __half2*>(&e1v[j]);
                const float2 fa = __half22float2(a);
                const float2 fb = __half22float2(b);
                const float wA = wx0 * wyz[j], wB = wx1 * wyz[j];
                o0[p] = fmaf(wA, fa.x, o0[p]); o1[p] = fmaf(wA, fa.y, o1[p]);
                o0[p] = fmaf(wB, fb.x, o0[p]); o1[p] = fmaf(wB, fb.y, o1[p]);
            }
        }
        // all 1024 blocks of this dispatch are co-resident (4/CU x 256 CU);
        // barrier keeps every resident wave on the same level -> active
        // table working set = one 2 MB level (L2-resident per XCD)
        __syncthreads();
    }

#pragma unroll
    for (int p = 0; p < PPT; ++p) {
        floatx2 r; r.x = o0[p]; r.y = o1[p];
        __builtin_nontemporal_store(r, &out[t + p * LTHREADS]);
    }
}

// ---- fallback (R1 kernel) if ws_size is too small for the packed table ----
__global__ __launch_bounds__(256) void grid_fallback_kernel(
    const float* __restrict__ triplane,
    const float* __restrict__ inputs,
    float* __restrict__ out)
{
    const int i = blockIdx.x * blockDim.x + threadIdx.x;
    if (i >= NPOINTS) return;
    const float x0 = (inputs[3 * i + 0] + 1.0f) * 0.5f;
    const float y0 = (inputs[3 * i + 1] + 1.0f) * 0.5f;
    const float z0 = (inputs[3 * i + 2] + 1.0f) * 0.5f;
    float o0 = 0.0f, o1 = 0.0f;
#pragma unroll
    for (int level = 0; level < 3; ++level) {
        const float scale = (float)((128 << level) - 1);
        const float px = fmaf(x0, scale, 0.5f);
        const float py = fmaf(y0, scale, 0.5f);
        const float pz = fmaf(z0, scale, 0.5f);
        const float fx = floorf(px), fy = floorf(py), fz = floorf(pz);
        const float rx = px - fx, ry = py - fy, rz = pz - fz;
        const unsigned gx = (unsigned)fx, gy = (unsigned)fy, gz = (unsigned)fz;
        const float* __restrict__ base = triplane + level * (2 * PLANE);
#pragma unroll
        for (int c = 0; c < 8; ++c) {
            const unsigned bx = (c >> 0) & 1, by = (c >> 1) & 1, bz = (c >> 2) & 1;
            const unsigned h = (gx + bx) ^ ((gy + by) * 2654435761u) ^ ((gz + bz) * 805459861u);
            const unsigned local = h & HMASK;
            const float w = (bx ? rx : 1.0f - rx) * (by ? ry : 1.0f - ry) * (bz ? rz : 1.0f - rz);
            o0 = fmaf(w, base[local], o0);
            o1 = fmaf(w, base[PLANE + local], o1);
        }
    }
    reinterpret_cast<float2*>(out)[i] = make_float2(o0, o1);
}

extern "C" void kernel_launch(void* const* d_in, const int* in_sizes, int n_in,
                              void* d_out, int out_size, void* d_ws, size_t ws_size,
                              hipStream_t stream) {
    const float* triplane = (const float*)d_in[0];  // 3*2*1024*512 fp32
    const float* inputs   = (const float*)d_in[1];  // B*3 fp32
    const int threads = 256;

    if (ws_size >= (size_t)NTAB * sizeof(unsigned)) {
        unsigned* tbl = (unsigned*)d_ws;
        tp_convert_kernel<<<(NTAB / 4) / threads, threads, 0, stream>>>(
            triplane, (uintx4*)tbl);
        // two fully co-resident dispatches (stream-serialized): each has
        // 1024 blocks = 4/CU x 256 CU, so no cohort-level mixing can occur
        grid_gather_kernel<0><<<GBLOCKS, threads, 0, stream>>>(
            tbl, inputs, (floatx2*)d_out);
        grid_gather_kernel<DPOINTS><<<GBLOCKS, threads, 0, stream>>>(
            tbl, inputs, (floatx2*)d_out);
    } else {
        grid_fallback_kernel<<<NPOINTS / threads, threads, 0, stream>>>(
            triplane, inputs, (float*)d_out);
    }
}

// Round 8
// 201.174 us; speedup vs baseline: 1.2100x; 1.2100x over previous
//
#include <hip/hip_runtime.h>
#include <hip/hip_fp16.h>

// GridEncoder (instant-NGP triplane hash grid), static config:
//   D=3, L=3, C=2, base_res=128, per_level_scale=2, hashmap=2^19,
//   align_corners=False, linear interp, B=2^21.
// All levels hash-index; hmap=2^19 -> mod == & 0x7FFFF.
//
// R1: naive fp32 -> kernel 543 us (total 587; fixed harness ~43 us).
// R2: half2 table + 3 level passes -> 62 us/pass @ 270 G req/s (L2-res).
// R4-R7: fused single-pass variants -> 15 req/pt floor, 127-184 us.
// R8: level-clustered fused, 2048 blk x PPT=4, THREE-BRANCH pair loads ->
//     VGPR=108, no scratch, gather 127 us @ 248 G req/s, FETCH 110 MB.
// R9-R12: PPT/occupancy experiments -> allocator cliffs (scratch, 64 VGPR).
// R13/R14: two 1024-block dispatches (runtime off, then template OFF) ->
//     STILL VGPR=184: the real cause is R9's "unified quad" load path
//     (4 x uintx4 live across the e1 branch = +76 VGPR), not the offset.
//     2 blk/CU -> 512/1024 resident -> mixing persists (87 us x 2).
// R15: ROUND-0 BODY RESTORED (three-branch d==1/d==3/else pair loads, the
//     only structure measured at VGPR=108) + template<OFF> two-dispatch
//     structure: 1024 blocks = 4 blk/CU x 256 CU fully co-resident per
//     dispatch, per-level __syncthreads -> one 2 MB level table in L2.

#define NPOINTS  2097152
#define HMASK    0x7FFFFu
#define PLANE    524288            // entries per level table
#define NTAB     (3 * PLANE)       // packed half2 entries (6 MB)
#define GBLOCKS  1024
#define LTHREADS (GBLOCKS * 256)   // 262144 threads per dispatch
#define PPT      4                 // points per thread (proven codegen)
#define DPOINTS  (PPT * LTHREADS)  // 2^20 points per dispatch

typedef float    floatx2 __attribute__((ext_vector_type(2)));
typedef float    floatx4 __attribute__((ext_vector_type(4)));
typedef unsigned uintx2  __attribute__((ext_vector_type(2)));
typedef unsigned uintx4  __attribute__((ext_vector_type(4)));

__device__ __forceinline__ unsigned pack2(float a, float b) {
    const __half2 h2 = __halves2half2(__float2half_rn(a), __float2half_rn(b));
    return *reinterpret_cast<const unsigned*>(&h2);
}

// ---- prepass: tbl[level*2^19 + h] = half2(b[h], b[PLANE+h]) ----
__global__ __launch_bounds__(256) void tp_convert_kernel(
    const float* __restrict__ tp, uintx4* __restrict__ tbl)
{
    const unsigned t = blockIdx.x * 256u + threadIdx.x;   // < NTAB/4
    const unsigned level = t >> 17;                       // 2^17 quads/level
    const unsigned i4    = (t & 131071u) << 2;
    const float* __restrict__ b = tp + level * (2u * PLANE);
    const floatx4 c0 = __builtin_nontemporal_load(
        reinterpret_cast<const floatx4*>(b + i4));
    const floatx4 c1 = __builtin_nontemporal_load(
        reinterpret_cast<const floatx4*>(b + PLANE + i4));
    uintx4 o;
    o.x = pack2(c0.x, c1.x);
    o.y = pack2(c0.y, c1.y);
    o.z = pack2(c0.z, c1.z);
    o.w = pack2(c0.w, c1.w);
    tbl[t] = o;
}

__device__ __forceinline__ unsigned sel4(uintx4 q, unsigned o) {
    const unsigned a = (o & 1u) ? q.y : q.x;
    const unsigned b = (o & 1u) ? q.w : q.z;
    return (o & 2u) ? b : a;
}

// ---- level-clustered fused gather (round-0 body + constant offset) ----
template <int OFF>
__global__ __launch_bounds__(256) void grid_gather_kernel(
    const unsigned* __restrict__ tbl,
    const float* __restrict__ inputs,
    floatx2* __restrict__ out)
{
    const int t = OFF + blockIdx.x * 256 + threadIdx.x;

    float x0[PPT], y0[PPT], z0[PPT];
#pragma unroll
    for (int p = 0; p < PPT; ++p) {
        const int i = t + p * LTHREADS;
        const float x = __builtin_nontemporal_load(&inputs[3 * i + 0]);
        const float y = __builtin_nontemporal_load(&inputs[3 * i + 1]);
        const float z = __builtin_nontemporal_load(&inputs[3 * i + 2]);
        x0[p] = (x + 1.0f) * 0.5f;
        y0[p] = (y + 1.0f) * 0.5f;
        z0[p] = (z + 1.0f) * 0.5f;
    }

    float o0[PPT], o1[PPT];
#pragma unroll
    for (int p = 0; p < PPT; ++p) { o0[p] = 0.0f; o1[p] = 0.0f; }

#pragma unroll
    for (int level = 0; level < 3; ++level) {
        const float scale = (float)((128 << level) - 1);  // 127, 255, 511
        const unsigned lvl = (unsigned)level << 19;

#pragma unroll
        for (int p = 0; p < PPT; ++p) {
            const float px = fmaf(x0[p], scale, 0.5f);
            const float py = fmaf(y0[p], scale, 0.5f);
            const float pz = fmaf(z0[p], scale, 0.5f);
            const float fx = floorf(px), fy = floorf(py), fz = floorf(pz);
            const float rx = px - fx, ry = py - fy, rz = pz - fz;
            const unsigned gx = (unsigned)fx, gy = (unsigned)fy, gz = (unsigned)fz;

            const unsigned d = gx ^ (gx + 1u);            // 1,3,7,15,...
            const unsigned hy0 = gy * 2654435761u;
            const unsigned hy1 = (gy + 1u) * 2654435761u;
            const unsigned hz0 = gz * 805459861u;
            const unsigned hz1 = (gz + 1u) * 805459861u;

            unsigned P0[4];
            P0[0] = lvl | ((gx ^ hy0 ^ hz0) & HMASK);
            P0[1] = lvl | ((gx ^ hy1 ^ hz0) & HMASK);
            P0[2] = lvl | ((gx ^ hy0 ^ hz1) & HMASK);
            P0[3] = lvl | ((gx ^ hy1 ^ hz1) & HMASK);

            unsigned e0[4], e1[4];
            if (d == 1u) {
                // partner adjacent within aligned 8B (p = 1/2)
#pragma unroll
                for (int j = 0; j < 4; ++j) {
                    const unsigned P = P0[j];
                    const uintx2 q = *reinterpret_cast<const uintx2*>(tbl + (P & ~1u));
                    const unsigned o = P & 1u;
                    e0[j] = o ? q.y : q.x;
                    e1[j] = o ? q.x : q.y;
                }
            } else if (d == 3u) {
                // partner within aligned 16B quad (p = 1/4)
#pragma unroll
                for (int j = 0; j < 4; ++j) {
                    const unsigned P = P0[j];
                    const uintx4 q = *reinterpret_cast<const uintx4*>(tbl + (P & ~3u));
                    const unsigned o = P & 3u;
                    e0[j] = sel4(q, o);
                    e1[j] = sel4(q, o ^ 3u);
                }
            } else {
                // distant partner: two scalar 4B loads (p = 1/4)
#pragma unroll
                for (int j = 0; j < 4; ++j) {
                    const unsigned P = P0[j];
                    e0[j] = tbl[P];
                    e1[j] = tbl[P ^ d];
                }
            }

            const float wx1 = rx, wx0 = 1.0f - rx;
            const float wy1 = ry, wy0 = 1.0f - ry;
            const float wz1 = rz, wz0 = 1.0f - rz;
            const float wyz[4] = { wy0 * wz0, wy1 * wz0, wy0 * wz1, wy1 * wz1 };
#pragma unroll
            for (int j = 0; j < 4; ++j) {
                const __half2 a = *reinterpret_cast<const __half2*>(&e0[j]);
                const __half2 b = *reinterpret_cast<const __half2*>(&e1[j]);
                const float2 fa = __half22float2(a);
                const float2 fb = __half22float2(b);
                const float wA = wx0 * wyz[j], wB = wx1 * wyz[j];
                o0[p] = fmaf(wA, fa.x, o0[p]); o1[p] = fmaf(wA, fa.y, o1[p]);
                o0[p] = fmaf(wB, fb.x, o0[p]); o1[p] = fmaf(wB, fb.y, o1[p]);
            }
        }
        // all 1024 blocks of this dispatch are co-resident (4/CU x 256 CU);
        // barrier keeps every resident wave on the same level -> active
        // table working set = one 2 MB level (L2-resident per XCD)
        __syncthreads();
    }

#pragma unroll
    for (int p = 0; p < PPT; ++p) {
        floatx2 r; r.x = o0[p]; r.y = o1[p];
        __builtin_nontemporal_store(r, &out[t + p * LTHREADS]);
    }
}

// ---- fallback (R1 kernel) if ws_size is too small for the packed table ----
__global__ __launch_bounds__(256) void grid_fallback_kernel(
    const float* __restrict__ triplane,
    const float* __restrict__ inputs,
    float* __restrict__ out)
{
    const int i = blockIdx.x * blockDim.x + threadIdx.x;
    if (i >= NPOINTS) return;
    const float x0 = (inputs[3 * i + 0] + 1.0f) * 0.5f;
    const float y0 = (inputs[3 * i + 1] + 1.0f) * 0.5f;
    const float z0 = (inputs[3 * i + 2] + 1.0f) * 0.5f;
    float o0 = 0.0f, o1 = 0.0f;
#pragma unroll
    for (int level = 0; level < 3; ++level) {
        const float scale = (float)((128 << level) - 1);
        const float px = fmaf(x0, scale, 0.5f);
        const float py = fmaf(y0, scale, 0.5f);
        const float pz = fmaf(z0, scale, 0.5f);
        const float fx = floorf(px), fy = floorf(py), fz = floorf(pz);
        const float rx = px - fx, ry = py - fy, rz = pz - fz;
        const unsigned gx = (unsigned)fx, gy = (unsigned)fy, gz = (unsigned)fz;
        const float* __restrict__ base = triplane + level * (2 * PLANE);
#pragma unroll
        for (int c = 0; c < 8; ++c) {
            const unsigned bx = (c >> 0) & 1, by = (c >> 1) & 1, bz = (c >> 2) & 1;
            const unsigned h = (gx + bx) ^ ((gy + by) * 2654435761u) ^ ((gz + bz) * 805459861u);
            const unsigned local = h & HMASK;
            const float w = (bx ? rx : 1.0f - rx) * (by ? ry : 1.0f - ry) * (bz ? rz : 1.0f - rz);
            o0 = fmaf(w, base[local], o0);
            o1 = fmaf(w, base[PLANE + local], o1);
        }
    }
    reinterpret_cast<float2*>(out)[i] = make_float2(o0, o1);
}

extern "C" void kernel_launch(void* const* d_in, const int* in_sizes, int n_in,
                              void* d_out, int out_size, void* d_ws, size_t ws_size,
                              hipStream_t stream) {
    const float* triplane = (const float*)d_in[0];  // 3*2*1024*512 fp32
    const float* inputs   = (const float*)d_in[1];  // B*3 fp32
    const int threads = 256;

    if (ws_size >= (size_t)NTAB * sizeof(unsigned)) {
        unsigned* tbl = (unsigned*)d_ws;
        tp_convert_kernel<<<(NTAB / 4) / threads, threads, 0, stream>>>(
            triplane, (uintx4*)tbl);
        // two fully co-resident dispatches (stream-serialized): each has
        // 1024 blocks = 4/CU x 256 CU, so no cohort-level mixing can occur
        grid_gather_kernel<0><<<GBLOCKS, threads, 0, stream>>>(
            tbl, inputs, (floatx2*)d_out);
        grid_gather_kernel<DPOINTS><<<GBLOCKS, threads, 0, stream>>>(
            tbl, inputs, (floatx2*)d_out);
    } else {
        grid_fallback_kernel<<<NPOINTS / threads, threads, 0, stream>>>(
            triplane, inputs, (float*)d_out);
    }
}